// Round 11
// baseline (344.780 us; speedup 1.0000x reference)
//
#include <hip/hip_runtime.h>
#include <hip/hip_fp16.h>

#define D 128

constexpr int SCAN_CHUNK = 1024;
constexpr int NRANGE = 8;    // dst ranges (one per XCD via blockIdx%8 heuristic)
constexpr int NCHUNK = 64;   // edge chunks
constexpr int RRC = 6272;    // max nodes per range supported by LDS arrays

using short8 = __attribute__((ext_vector_type(8))) short;
using f32x4 = __attribute__((ext_vector_type(4))) float;

// split fp32 into hi/lo bf16 (truncation; residual exact in fp32)
__device__ inline void splitf(float v, unsigned short& h, unsigned short& l) {
    unsigned b = __float_as_uint(v);
    h = (unsigned short)(b >> 16);
    float fh = __uint_as_float(b & 0xffff0000u);
    float r = v - fh;
    l = (unsigned short)(__float_as_uint(r) >> 16);
}

// ---------------- CSR build: XCD-partitioned counting sort, no global atomics ----------------

__global__ __launch_bounds__(1024) void hist_count(
    const int* __restrict__ dst, int* __restrict__ hist,
    int n_edges, int n_nodes, int rr, int ch) {
    __shared__ int lh[RRC];
    int b = blockIdx.x;
    int r = b & (NRANGE - 1), c = b >> 3;
    int t = threadIdx.x;
    for (int i = t; i < rr; i += 1024) lh[i] = 0;
    __syncthreads();
    int lo = r * rr, hi = min(n_nodes, lo + rr);
    int e0 = c * ch, e1 = min(n_edges, e0 + ch);
    for (int e = e0 + t; e < e1; e += 1024) {
        int d = dst[e];
        if (d >= lo && d < hi) atomicAdd(&lh[d - lo], 1);
    }
    __syncthreads();
    int* gh = hist + (size_t)(r * NCHUNK + c) * rr;
    for (int i = t; i < rr; i += 1024) gh[i] = lh[i];
}

__global__ __launch_bounds__(256) void deg_sum(
    const int* __restrict__ hist, int* __restrict__ deg, int n_nodes, int rr) {
    int i = blockIdx.x * 256 + threadIdx.x;
    if (i >= n_nodes) return;
    int r = i / rr, ii = i - r * rr;
    int s = 0;
    for (int c = 0; c < NCHUNK; ++c) s += hist[(size_t)(r * NCHUNK + c) * rr + ii];
    deg[i] = s;
}

__global__ void partial_sums(const int* __restrict__ deg, int* __restrict__ partials, int n) {
    __shared__ int sdata[256];
    int b = blockIdx.x, t = threadIdx.x;
    int base = b * SCAN_CHUNK;
    int sum = 0;
    for (int i = t; i < SCAN_CHUNK; i += 256) {
        int idx = base + i;
        if (idx < n) sum += deg[idx];
    }
    sdata[t] = sum;
    __syncthreads();
    for (int st = 128; st > 0; st >>= 1) {
        if (t < st) sdata[t] += sdata[t + st];
        __syncthreads();
    }
    if (t == 0) partials[b] = sdata[0];
}

__global__ void scan_partials(int* __restrict__ partials, int nb, int* __restrict__ total) {
    if (threadIdx.x == 0 && blockIdx.x == 0) {
        int run = 0;
        for (int i = 0; i < nb; ++i) { int v = partials[i]; partials[i] = run; run += v; }
        *total = run;
    }
}

__global__ void scan_chunks(const int* __restrict__ deg, const int* __restrict__ partials,
                            int* __restrict__ row_ptr, float* __restrict__ inv_deg, int n) {
    __shared__ int soff[256];
    int b = blockIdx.x, t = threadIdx.x;
    int base = b * SCAN_CHUNK;
    int i0 = base + t * 4;
    int v[4];
    int s = 0;
#pragma unroll
    for (int j = 0; j < 4; ++j) {
        int idx = i0 + j;
        v[j] = (idx < n) ? deg[idx] : 0;
        s += v[j];
    }
    soff[t] = s;
    __syncthreads();
    for (int d = 1; d < 256; d <<= 1) {
        int val = (t >= d) ? soff[t - d] : 0;
        __syncthreads();
        soff[t] += val;
        __syncthreads();
    }
    int excl = soff[t] - s + partials[b];
#pragma unroll
    for (int j = 0; j < 4; ++j) {
        int idx = i0 + j;
        if (idx < n) {
            row_ptr[idx] = excl;
            int dv = v[j] > 1 ? v[j] : 1;
            inv_deg[idx] = 1.0f / (float)dv;
            excl += v[j];
        }
    }
}

__global__ __launch_bounds__(256) void base_fill(
    const int* __restrict__ hist, const int* __restrict__ row_ptr,
    int* __restrict__ base, int n_nodes, int rr) {
    int i = blockIdx.x * 256 + threadIdx.x;
    if (i >= n_nodes) return;
    int r = i / rr, ii = i - r * rr;
    int b = row_ptr[i];
    for (int c = 0; c < NCHUNK; ++c) {
        size_t idx = (size_t)(r * NCHUNK + c) * rr + ii;
        base[idx] = b;
        b += hist[idx];
    }
}

__global__ __launch_bounds__(1024) void fill_part(
    const int* __restrict__ src, const int* __restrict__ dst,
    const int* __restrict__ base, int* __restrict__ csr,
    int n_edges, int n_nodes, int rr, int ch) {
    __shared__ int cur[RRC];
    int b = blockIdx.x;
    int r = b & (NRANGE - 1), c = b >> 3;
    int t = threadIdx.x;
    const int* gb = base + (size_t)(r * NCHUNK + c) * rr;
    for (int i = t; i < rr; i += 1024) cur[i] = gb[i];
    __syncthreads();
    int lo = r * rr, hi = min(n_nodes, lo + rr);
    int e0 = c * ch, e1 = min(n_edges, e0 + ch);
    for (int e = e0 + t; e < e1; e += 1024) {
        int d = dst[e];
        if (d >= lo && d < hi) {
            int slot = atomicAdd(&cur[d - lo], 1);
            csr[slot] = src[e];
        }
    }
}

// ---------------- weight split+transpose: W[K=128][N] -> Wt_hi/lo [N][128] ----------------
struct WSplitArgs {
    const float* src[6];
    unsigned short* dh[6];
    unsigned short* dl[6];
    int n[6];
};

__global__ __launch_bounds__(256) void split_w(WSplitArgs a) {
    int m = blockIdx.y;
    int N = a.n[m];
    int e = blockIdx.x * 256 + threadIdx.x;
    if (e >= 128 * N) return;
    int sh = (N == 128) ? 7 : 6;
    int k = e >> sh;
    int n = e & (N - 1);
    float v = a.src[m][e];
    unsigned short h, l;
    splitf(v, h, l);
    a.dh[m][n * 128 + k] = h;
    a.dl[m][n * 128 + k] = l;
}

// ---------------- MFMA GEMM (LDS-staged, fused P+Q) ----------------
template <int BN, int NT, bool SPLITX>
__global__ __launch_bounds__(256) void gemm_lds(
    const float* __restrict__ X,
    const unsigned short* __restrict__ Ah, const unsigned short* __restrict__ Al,
    const unsigned short* __restrict__ W1h, const unsigned short* __restrict__ W1l,
    const unsigned short* __restrict__ W2h, const unsigned short* __restrict__ W2l,
    const float* __restrict__ bias, __half* __restrict__ P, float* __restrict__ Q, int M) {
    __shared__ short8 As[2][16 * 65];   // [hi/lo][col16*65 + row], 33.3 KB

    const int tid = threadIdx.x;
    const int wave = tid >> 6;
    const int lane = tid & 63;
    const int l15 = lane & 15;
    const int q = lane >> 4;
    const int m0 = blockIdx.x * 64;

    if constexpr (SPLITX) {
#pragma unroll
        for (int it = 0; it < 4; ++it) {
            int s = it * 256 + tid;
            int row = s >> 4, col16 = s & 15;
            int gr = min(m0 + row, M - 1);
            const float4* xp = (const float4*)X + (size_t)gr * 32 + col16 * 2;
            float4 v0 = xp[0], v1 = xp[1];
            float fv[8] = {v0.x, v0.y, v0.z, v0.w, v1.x, v1.y, v1.z, v1.w};
            short8 h, l;
#pragma unroll
            for (int j = 0; j < 8; ++j) {
                unsigned short hh_, ll_;
                splitf(fv[j], hh_, ll_);
                h[j] = (short)hh_;
                l[j] = (short)ll_;
            }
            As[0][col16 * 65 + row] = h;
            As[1][col16 * 65 + row] = l;
        }
    } else {
#pragma unroll
        for (int it = 0; it < 8; ++it) {
            int s = it * 256 + tid;
            int arr = s >> 10;
            int sp = s & 1023;
            int row = sp >> 4, col16 = sp & 15;
            int gr = min(m0 + row, M - 1);
            const unsigned short* src = (arr ? Al : Ah) + (size_t)gr * 128 + col16 * 8;
            As[arr][col16 * 65 + row] = *(const short8*)src;
        }
    }
    __syncthreads();

    const int isQ = wave >> 1;
    const int colbase = (wave & 1) * (NT * 16);
    const unsigned short* Wh = isQ ? W2h : W1h;
    const unsigned short* Wl = isQ ? W2l : W1l;

    float bvs[NT];
#pragma unroll
    for (int nt = 0; nt < NT; ++nt) bvs[nt] = isQ ? bias[colbase + nt * 16 + l15] : 0.f;

    f32x4 acc[4][NT] = {};

#pragma unroll 1
    for (int kt = 0; kt < 4; ++kt) {
        short8 Bh[NT], Bl[NT];
#pragma unroll
        for (int nt = 0; nt < NT; ++nt) {
            int c = colbase + nt * 16 + l15;
            int off = c * 128 + kt * 32 + q * 8;
            Bh[nt] = *(const short8*)(Wh + off);
            Bl[nt] = *(const short8*)(Wl + off);
        }
#pragma unroll
        for (int mt = 0; mt < 4; ++mt) {
            int ai = (kt * 4 + q) * 65 + mt * 16 + l15;
            short8 Afh = As[0][ai];
            short8 Afl = As[1][ai];
#pragma unroll
            for (int nt = 0; nt < NT; ++nt) {
                acc[mt][nt] = __builtin_amdgcn_mfma_f32_16x16x32_bf16(Afh, Bh[nt], acc[mt][nt], 0, 0, 0);
                acc[mt][nt] = __builtin_amdgcn_mfma_f32_16x16x32_bf16(Afh, Bl[nt], acc[mt][nt], 0, 0, 0);
                acc[mt][nt] = __builtin_amdgcn_mfma_f32_16x16x32_bf16(Afl, Bh[nt], acc[mt][nt], 0, 0, 0);
            }
        }
    }

#pragma unroll
    for (int mt = 0; mt < 4; ++mt) {
        int orow = m0 + mt * 16 + q * 4;
#pragma unroll
        for (int nt = 0; nt < NT; ++nt) {
            int col = colbase + nt * 16 + l15;
#pragma unroll
            for (int r = 0; r < 4; ++r) {
                int rr = orow + r;
                if (rr < M) {
                    if (isQ) Q[(size_t)rr * BN + col] = acc[mt][nt][r] + bvs[nt];
                    else P[(size_t)rr * BN + col] = __float2half(acc[mt][nt][r]);
                }
            }
        }
    }
}

// ---------------- fused aggregation 128-dim, fp16 gather, 16B/lane ----------------
// 4 edges per wave-instruction: quarter = lane>>4 picks edge slot;
// 16 lanes x half8(16B) = one 256B row. x2 unroll -> 8 edges in flight.
__global__ __launch_bounds__(256) void agg_fused128(
    const __half* __restrict__ P, const float* __restrict__ Q,
    const int* __restrict__ row_ptr, const int* __restrict__ csr,
    const float* __restrict__ inv_deg, unsigned short* __restrict__ Hh,
    unsigned short* __restrict__ Hl, int n_nodes) {
    int node = (blockIdx.x * blockDim.x + threadIdx.x) >> 6;
    int lane = threadIdx.x & 63;
    if (node >= n_nodes) return;
    int beg = row_ptr[node], end = row_ptr[node + 1];
    const int quarter = lane >> 4;
    const int l = lane & 15;   // covers dims 8l..8l+7
    float a[2][8] = {};
    int e = beg;
    for (; e + 8 <= end; e += 8) {
#pragma unroll
        for (int j = 0; j < 2; ++j) {
            int s = csr[e + 4 * j + quarter];
            uint4 raw = *(const uint4*)(P + (size_t)s * 128 + l * 8);
            float2 f0 = __half22float2(*reinterpret_cast<__half2*>(&raw.x));
            float2 f1 = __half22float2(*reinterpret_cast<__half2*>(&raw.y));
            float2 f2 = __half22float2(*reinterpret_cast<__half2*>(&raw.z));
            float2 f3 = __half22float2(*reinterpret_cast<__half2*>(&raw.w));
            a[j][0] += f0.x; a[j][1] += f0.y; a[j][2] += f1.x; a[j][3] += f1.y;
            a[j][4] += f2.x; a[j][5] += f2.y; a[j][6] += f3.x; a[j][7] += f3.y;
        }
    }
    for (; e < end; e += 4) {
        int idx = e + quarter;
        if (idx < end) {
            int s = csr[idx];
            uint4 raw = *(const uint4*)(P + (size_t)s * 128 + l * 8);
            float2 f0 = __half22float2(*reinterpret_cast<__half2*>(&raw.x));
            float2 f1 = __half22float2(*reinterpret_cast<__half2*>(&raw.y));
            float2 f2 = __half22float2(*reinterpret_cast<__half2*>(&raw.z));
            float2 f3 = __half22float2(*reinterpret_cast<__half2*>(&raw.w));
            a[0][0] += f0.x; a[0][1] += f0.y; a[0][2] += f1.x; a[0][3] += f1.y;
            a[0][4] += f2.x; a[0][5] += f2.y; a[0][6] += f3.x; a[0][7] += f3.y;
        }
    }
    float s[8];
#pragma unroll
    for (int k = 0; k < 8; ++k) {
        s[k] = a[0][k] + a[1][k];
        s[k] += __shfl_xor(s[k], 16);
        s[k] += __shfl_xor(s[k], 32);
    }
    if (lane < 16) {
        float w = inv_deg[node];
        const float4* Q4 = (const float4*)(Q + (size_t)node * 128 + l * 8);
        float4 q0 = Q4[0], q1 = Q4[1];
        float qv[8] = {q0.x, q0.y, q0.z, q0.w, q1.x, q1.y, q1.z, q1.w};
        short8 hv, lv;
#pragma unroll
        for (int k = 0; k < 8; ++k) {
            float h = fmaxf(fmaf(s[k], w, qv[k]), 0.f);
            unsigned short hh_, ll_;
            splitf(h, hh_, ll_);
            hv[k] = (short)hh_;
            lv[k] = (short)ll_;
        }
        *(short8*)(Hh + (size_t)node * 128 + l * 8) = hv;
        *(short8*)(Hl + (size_t)node * 128 + l * 8) = lv;
    }
}

// ---------------- fused aggregation 64-dim (fp16 gather, 16B/lane) + output head ----------------
// 8 edges per wave-instruction: oct = lane>>3; 8 lanes x half8(16B) = one 128B row.
__global__ __launch_bounds__(256) void agg64_head(
    const __half* __restrict__ P, const float* __restrict__ Q,
    const int* __restrict__ row_ptr, const int* __restrict__ csr,
    const float* __restrict__ inv_deg, const float* __restrict__ Wo,
    const float* __restrict__ bo, float* __restrict__ out, int n_nodes) {
    int node = (blockIdx.x * blockDim.x + threadIdx.x) >> 6;
    int lane = threadIdx.x & 63;
    if (node >= n_nodes) return;
    int beg = row_ptr[node], end = row_ptr[node + 1];
    const int oct = lane >> 3;
    const int l = lane & 7;    // covers dims 8l..8l+7
    float a[8] = {};
    int e = beg;
    for (; e + 8 <= end; e += 8) {
        int s = csr[e + oct];
        uint4 raw = *(const uint4*)(P + (size_t)s * 64 + l * 8);
        float2 f0 = __half22float2(*reinterpret_cast<__half2*>(&raw.x));
        float2 f1 = __half22float2(*reinterpret_cast<__half2*>(&raw.y));
        float2 f2 = __half22float2(*reinterpret_cast<__half2*>(&raw.z));
        float2 f3 = __half22float2(*reinterpret_cast<__half2*>(&raw.w));
        a[0] += f0.x; a[1] += f0.y; a[2] += f1.x; a[3] += f1.y;
        a[4] += f2.x; a[5] += f2.y; a[6] += f3.x; a[7] += f3.y;
    }
    if (e < end) {
        int idx = e + oct;
        if (idx < end) {
            int s = csr[idx];
            uint4 raw = *(const uint4*)(P + (size_t)s * 64 + l * 8);
            float2 f0 = __half22float2(*reinterpret_cast<__half2*>(&raw.x));
            float2 f1 = __half22float2(*reinterpret_cast<__half2*>(&raw.y));
            float2 f2 = __half22float2(*reinterpret_cast<__half2*>(&raw.z));
            float2 f3 = __half22float2(*reinterpret_cast<__half2*>(&raw.w));
            a[0] += f0.x; a[1] += f0.y; a[2] += f1.x; a[3] += f1.y;
            a[4] += f2.x; a[5] += f2.y; a[6] += f3.x; a[7] += f3.y;
        }
    }
    // butterfly over octs -> every lane holds full sums for its 8 dims
#pragma unroll
    for (int k = 0; k < 8; ++k) {
        a[k] += __shfl_xor(a[k], 8);
        a[k] += __shfl_xor(a[k], 16);
        a[k] += __shfl_xor(a[k], 32);
    }
    float w = inv_deg[node];
    const float4* Q4 = (const float4*)(Q + (size_t)node * 64 + l * 8);
    float4 q0 = Q4[0], q1 = Q4[1];
    float qv[8] = {q0.x, q0.y, q0.z, q0.w, q1.x, q1.y, q1.z, q1.w};
    const float4* Wo4 = (const float4*)Wo;
    float c0 = 0.f, c1 = 0.f, c2 = 0.f, c3 = 0.f;
#pragma unroll
    for (int k = 0; k < 8; ++k) {
        float h = fmaxf(fmaf(a[k], w, qv[k]), 0.f);
        float4 wv = Wo4[l * 8 + k];
        c0 = fmaf(h, wv.x, c0);
        c1 = fmaf(h, wv.y, c1);
        c2 = fmaf(h, wv.z, c2);
        c3 = fmaf(h, wv.w, c3);
    }
#pragma unroll
    for (int m = 4; m > 0; m >>= 1) {
        c0 += __shfl_xor(c0, m);
        c1 += __shfl_xor(c1, m);
        c2 += __shfl_xor(c2, m);
        c3 += __shfl_xor(c3, m);
    }
    if (lane == 0) {
        float4 r;
        r.x = c0 + bo[0];
        r.y = c1 + bo[1];
        r.z = c2 + bo[2];
        r.w = c3 + bo[3];
        ((float4*)out)[node] = r;
    }
}

extern "C" void kernel_launch(void* const* d_in, const int* in_sizes, int n_in,
                              void* d_out, int out_size, void* d_ws, size_t ws_size,
                              hipStream_t stream) {
    const float* x = (const float*)d_in[0];
    const int* ei = (const int*)d_in[1];
    const float* wl0 = (const float*)d_in[3];
    const float* wr0 = (const float*)d_in[4];
    const float* b0 = (const float*)d_in[5];
    const float* wl1 = (const float*)d_in[6];
    const float* wr1 = (const float*)d_in[7];
    const float* b1 = (const float*)d_in[8];
    const float* wl2 = (const float*)d_in[9];
    const float* wr2 = (const float*)d_in[10];
    const float* b2 = (const float*)d_in[11];
    const float* wo = (const float*)d_in[12];
    const float* bo = (const float*)d_in[13];

    const int n_nodes = in_sizes[0] / D;   // 50000
    const int n_edges = in_sizes[1] / 2;   // 800000
    const int* srcp = ei;
    const int* dstp = ei + n_edges;

    char* ws = (char*)d_ws;
    size_t off = 0;
    auto carve = [&](size_t bytes) -> void* {
        void* p = ws + off;
        off = (off + bytes + 255) & ~(size_t)255;
        return p;
    };
    int* deg = (int*)carve((size_t)n_nodes * 4);
    int* row_ptr = (int*)carve((size_t)(n_nodes + 1) * 4);
    int* partials = (int*)carve(256 * 4);
    float* inv_deg = (float*)carve((size_t)n_nodes * 4);
    int* csr = (int*)carve((size_t)n_edges * 4);
    __half* Pbuf = (__half*)carve((size_t)n_nodes * D * 2);   // 12.8 MB
    float* Qbuf = (float*)carve((size_t)n_nodes * D * 4);     // 25.6 MB
    unsigned short* hh = (unsigned short*)carve((size_t)n_nodes * D * 2);
    unsigned short* hl = (unsigned short*)carve((size_t)n_nodes * D * 2);
    unsigned short* wt = (unsigned short*)carve((size_t)(4 * 128 * 128 + 2 * 64 * 128) * 2 * 2);
    unsigned short* wl0h = wt;
    unsigned short* wl0l = wl0h + 128 * 128;
    unsigned short* wr0h = wl0l + 128 * 128;
    unsigned short* wr0l = wr0h + 128 * 128;
    unsigned short* wl1h = wr0l + 128 * 128;
    unsigned short* wl1l = wl1h + 128 * 128;
    unsigned short* wr1h = wl1l + 128 * 128;
    unsigned short* wr1l = wr1h + 128 * 128;
    unsigned short* wl2h = wr1l + 128 * 128;
    unsigned short* wl2l = wl2h + 64 * 128;
    unsigned short* wr2h = wl2l + 64 * 128;
    unsigned short* wr2l = wr2h + 64 * 128;

    // CSR-build scratch aliases P/Q (dead until first GEMM):
    const int rr = (n_nodes + NRANGE - 1) / NRANGE;        // 6250
    const int ch = (n_edges + NCHUNK - 1) / NCHUNK;        // 12500
    int* hist = (int*)Qbuf;
    int* basep = (int*)Pbuf;

    const int nchunk_scan = (n_nodes + SCAN_CHUNK - 1) / SCAN_CHUNK;

    hist_count<<<NRANGE * NCHUNK, 1024, 0, stream>>>(dstp, hist, n_edges, n_nodes, rr, ch);
    deg_sum<<<(n_nodes + 255) / 256, 256, 0, stream>>>(hist, deg, n_nodes, rr);
    partial_sums<<<nchunk_scan, 256, 0, stream>>>(deg, partials, n_nodes);
    scan_partials<<<1, 64, 0, stream>>>(partials, nchunk_scan, row_ptr + n_nodes);
    scan_chunks<<<nchunk_scan, 256, 0, stream>>>(deg, partials, row_ptr, inv_deg, n_nodes);
    base_fill<<<(n_nodes + 255) / 256, 256, 0, stream>>>(hist, row_ptr, basep, n_nodes, rr);
    fill_part<<<NRANGE * NCHUNK, 1024, 0, stream>>>(srcp, dstp, basep, csr, n_edges, n_nodes, rr, ch);

    WSplitArgs wa;
    wa.src[0] = wl0; wa.dh[0] = wl0h; wa.dl[0] = wl0l; wa.n[0] = 128;
    wa.src[1] = wr0; wa.dh[1] = wr0h; wa.dl[1] = wr0l; wa.n[1] = 128;
    wa.src[2] = wl1; wa.dh[2] = wl1h; wa.dl[2] = wl1l; wa.n[2] = 128;
    wa.src[3] = wr1; wa.dh[3] = wr1h; wa.dl[3] = wr1l; wa.n[3] = 128;
    wa.src[4] = wl2; wa.dh[4] = wl2h; wa.dl[4] = wl2l; wa.n[4] = 64;
    wa.src[5] = wr2; wa.dh[5] = wr2h; wa.dl[5] = wr2l; wa.n[5] = 64;
    split_w<<<dim3(64, 6), 256, 0, stream>>>(wa);

    const int agg_blocks = (n_nodes * 64 + 255) / 256;
    const int gemm_blocks = (n_nodes + 63) / 64;   // 782

    // layer 0: A = x (fp32, split during LDS staging)
    gemm_lds<128, 4, true><<<gemm_blocks, 256, 0, stream>>>(
        x, nullptr, nullptr, wl0h, wl0l, wr0h, wr0l, b0, Pbuf, Qbuf, n_nodes);
    agg_fused128<<<agg_blocks, 256, 0, stream>>>(Pbuf, Qbuf, row_ptr, csr, inv_deg, hh, hl, n_nodes);
    // layer 1
    gemm_lds<128, 4, false><<<gemm_blocks, 256, 0, stream>>>(
        nullptr, hh, hl, wl1h, wl1l, wr1h, wr1l, b1, Pbuf, Qbuf, n_nodes);
    agg_fused128<<<agg_blocks, 256, 0, stream>>>(Pbuf, Qbuf, row_ptr, csr, inv_deg, hh, hl, n_nodes);
    // layer 2 (each matrix 64 cols)
    gemm_lds<64, 2, false><<<gemm_blocks, 256, 0, stream>>>(
        nullptr, hh, hl, wl2h, wl2l, wr2h, wr2l, b2, Pbuf, Qbuf, n_nodes);
    agg64_head<<<agg_blocks, 256, 0, stream>>>(Pbuf, Qbuf, row_ptr, csr, inv_deg,
                                               wo, bo, (float*)d_out, n_nodes);
}

// Round 12
// 325.739 us; speedup vs baseline: 1.0585x; 1.0585x over previous
//
#include <hip/hip_runtime.h>
#include <hip/hip_fp16.h>

#define D 128

constexpr int SCAN_CHUNK = 1024;
constexpr int NRANGE = 8;    // dst ranges (one per XCD via blockIdx%8 heuristic)
constexpr int NCHUNK = 64;   // edge chunks
constexpr int RRC = 6272;    // max nodes per range supported by LDS arrays

using short8 = __attribute__((ext_vector_type(8))) short;
using f32x4 = __attribute__((ext_vector_type(4))) float;

// split fp32 into hi/lo bf16 (truncation; residual exact in fp32)
__device__ inline void splitf(float v, unsigned short& h, unsigned short& l) {
    unsigned b = __float_as_uint(v);
    h = (unsigned short)(b >> 16);
    float fh = __uint_as_float(b & 0xffff0000u);
    float r = v - fh;
    l = (unsigned short)(__float_as_uint(r) >> 16);
}

// ---------------- CSR build: XCD-partitioned counting sort, no global atomics ----------------

__global__ __launch_bounds__(1024) void hist_count(
    const int* __restrict__ dst, int* __restrict__ hist,
    int n_edges, int n_nodes, int rr, int ch) {
    __shared__ int lh[RRC];
    int b = blockIdx.x;
    int r = b & (NRANGE - 1), c = b >> 3;
    int t = threadIdx.x;
    for (int i = t; i < rr; i += 1024) lh[i] = 0;
    __syncthreads();
    int lo = r * rr, hi = min(n_nodes, lo + rr);
    int e0 = c * ch, e1 = min(n_edges, e0 + ch);
    for (int e = e0 + t; e < e1; e += 1024) {
        int d = dst[e];
        if (d >= lo && d < hi) atomicAdd(&lh[d - lo], 1);
    }
    __syncthreads();
    int* gh = hist + (size_t)(r * NCHUNK + c) * rr;
    for (int i = t; i < rr; i += 1024) gh[i] = lh[i];
}

// deg[i] = sum over chunks + per-1024-chunk partial sums (merged deg_sum+partial_sums)
__global__ __launch_bounds__(256) void deg_partial(
    const int* __restrict__ hist, int* __restrict__ deg,
    int* __restrict__ partials, int n_nodes, int rr) {
    __shared__ int sdata[256];
    int b = blockIdx.x, t = threadIdx.x;
    int sum = 0;
#pragma unroll
    for (int jj = 0; jj < 4; ++jj) {
        int i = b * SCAN_CHUNK + jj * 256 + t;
        if (i < n_nodes) {
            int r = i / rr, ii = i - r * rr;
            int s = 0;
            for (int c = 0; c < NCHUNK; ++c) s += hist[(size_t)(r * NCHUNK + c) * rr + ii];
            deg[i] = s;
            sum += s;
        }
    }
    sdata[t] = sum;
    __syncthreads();
    for (int st = 128; st > 0; st >>= 1) {
        if (t < st) sdata[t] += sdata[t + st];
        __syncthreads();
    }
    if (t == 0) partials[b] = sdata[0];
}

__global__ void scan_partials(int* __restrict__ partials, int nb, int* __restrict__ total) {
    if (threadIdx.x == 0 && blockIdx.x == 0) {
        int run = 0;
        for (int i = 0; i < nb; ++i) { int v = partials[i]; partials[i] = run; run += v; }
        *total = run;
    }
}

__global__ void scan_chunks(const int* __restrict__ deg, const int* __restrict__ partials,
                            int* __restrict__ row_ptr, float* __restrict__ inv_deg, int n) {
    __shared__ int soff[256];
    int b = blockIdx.x, t = threadIdx.x;
    int base = b * SCAN_CHUNK;
    int i0 = base + t * 4;
    int v[4];
    int s = 0;
#pragma unroll
    for (int j = 0; j < 4; ++j) {
        int idx = i0 + j;
        v[j] = (idx < n) ? deg[idx] : 0;
        s += v[j];
    }
    soff[t] = s;
    __syncthreads();
    for (int d = 1; d < 256; d <<= 1) {
        int val = (t >= d) ? soff[t - d] : 0;
        __syncthreads();
        soff[t] += val;
        __syncthreads();
    }
    int excl = soff[t] - s + partials[b];
#pragma unroll
    for (int j = 0; j < 4; ++j) {
        int idx = i0 + j;
        if (idx < n) {
            row_ptr[idx] = excl;
            int dv = v[j] > 1 ? v[j] : 1;
            inv_deg[idx] = 1.0f / (float)dv;
            excl += v[j];
        }
    }
}

__global__ __launch_bounds__(256) void base_fill(
    const int* __restrict__ hist, const int* __restrict__ row_ptr,
    int* __restrict__ base, int n_nodes, int rr) {
    int i = blockIdx.x * 256 + threadIdx.x;
    if (i >= n_nodes) return;
    int r = i / rr, ii = i - r * rr;
    int b = row_ptr[i];
    for (int c = 0; c < NCHUNK; ++c) {
        size_t idx = (size_t)(r * NCHUNK + c) * rr + ii;
        base[idx] = b;
        b += hist[idx];
    }
}

__global__ __launch_bounds__(1024) void fill_part(
    const int* __restrict__ src, const int* __restrict__ dst,
    const int* __restrict__ base, int* __restrict__ csr,
    int n_edges, int n_nodes, int rr, int ch) {
    __shared__ int cur[RRC];
    int b = blockIdx.x;
    int r = b & (NRANGE - 1), c = b >> 3;
    int t = threadIdx.x;
    const int* gb = base + (size_t)(r * NCHUNK + c) * rr;
    for (int i = t; i < rr; i += 1024) cur[i] = gb[i];
    __syncthreads();
    int lo = r * rr, hi = min(n_nodes, lo + rr);
    int e0 = c * ch, e1 = min(n_edges, e0 + ch);
    for (int e = e0 + t; e < e1; e += 1024) {
        int d = dst[e];
        if (d >= lo && d < hi) {
            int slot = atomicAdd(&cur[d - lo], 1);
            csr[slot] = src[e];
        }
    }
}

// ---------------- weight split+transpose: W[K=128][N] -> Wt_hi/lo [N][128] ----------------
struct WSplitArgs {
    const float* src[6];
    unsigned short* dh[6];
    unsigned short* dl[6];
    int n[6];
};

__global__ __launch_bounds__(256) void split_w(WSplitArgs a) {
    int m = blockIdx.y;
    int N = a.n[m];
    int e = blockIdx.x * 256 + threadIdx.x;
    if (e >= 128 * N) return;
    int sh = (N == 128) ? 7 : 6;
    int k = e >> sh;
    int n = e & (N - 1);
    float v = a.src[m][e];
    unsigned short h, l;
    splitf(v, h, l);
    a.dh[m][n * 128 + k] = h;
    a.dl[m][n * 128 + k] = l;
}

// ---------------- MFMA GEMM (LDS-staged, fused P+Q) ----------------
template <int BN, int NT, bool SPLITX>
__global__ __launch_bounds__(256) void gemm_lds(
    const float* __restrict__ X,
    const unsigned short* __restrict__ Ah, const unsigned short* __restrict__ Al,
    const unsigned short* __restrict__ W1h, const unsigned short* __restrict__ W1l,
    const unsigned short* __restrict__ W2h, const unsigned short* __restrict__ W2l,
    const float* __restrict__ bias, __half* __restrict__ P, float* __restrict__ Q, int M) {
    __shared__ short8 As[2][16 * 65];   // [hi/lo][col16*65 + row], 33.3 KB

    const int tid = threadIdx.x;
    const int wave = tid >> 6;
    const int lane = tid & 63;
    const int l15 = lane & 15;
    const int q = lane >> 4;
    const int m0 = blockIdx.x * 64;

    if constexpr (SPLITX) {
#pragma unroll
        for (int it = 0; it < 4; ++it) {
            int s = it * 256 + tid;
            int row = s >> 4, col16 = s & 15;
            int gr = min(m0 + row, M - 1);
            const float4* xp = (const float4*)X + (size_t)gr * 32 + col16 * 2;
            float4 v0 = xp[0], v1 = xp[1];
            float fv[8] = {v0.x, v0.y, v0.z, v0.w, v1.x, v1.y, v1.z, v1.w};
            short8 h, l;
#pragma unroll
            for (int j = 0; j < 8; ++j) {
                unsigned short hh_, ll_;
                splitf(fv[j], hh_, ll_);
                h[j] = (short)hh_;
                l[j] = (short)ll_;
            }
            As[0][col16 * 65 + row] = h;
            As[1][col16 * 65 + row] = l;
        }
    } else {
#pragma unroll
        for (int it = 0; it < 8; ++it) {
            int s = it * 256 + tid;
            int arr = s >> 10;
            int sp = s & 1023;
            int row = sp >> 4, col16 = sp & 15;
            int gr = min(m0 + row, M - 1);
            const unsigned short* src = (arr ? Al : Ah) + (size_t)gr * 128 + col16 * 8;
            As[arr][col16 * 65 + row] = *(const short8*)src;
        }
    }
    __syncthreads();

    const int isQ = wave >> 1;
    const int colbase = (wave & 1) * (NT * 16);
    const unsigned short* Wh = isQ ? W2h : W1h;
    const unsigned short* Wl = isQ ? W2l : W1l;

    float bvs[NT];
#pragma unroll
    for (int nt = 0; nt < NT; ++nt) bvs[nt] = isQ ? bias[colbase + nt * 16 + l15] : 0.f;

    f32x4 acc[4][NT] = {};

#pragma unroll 1
    for (int kt = 0; kt < 4; ++kt) {
        short8 Bh[NT], Bl[NT];
#pragma unroll
        for (int nt = 0; nt < NT; ++nt) {
            int c = colbase + nt * 16 + l15;
            int off = c * 128 + kt * 32 + q * 8;
            Bh[nt] = *(const short8*)(Wh + off);
            Bl[nt] = *(const short8*)(Wl + off);
        }
#pragma unroll
        for (int mt = 0; mt < 4; ++mt) {
            int ai = (kt * 4 + q) * 65 + mt * 16 + l15;
            short8 Afh = As[0][ai];
            short8 Afl = As[1][ai];
#pragma unroll
            for (int nt = 0; nt < NT; ++nt) {
                acc[mt][nt] = __builtin_amdgcn_mfma_f32_16x16x32_bf16(Afh, Bh[nt], acc[mt][nt], 0, 0, 0);
                acc[mt][nt] = __builtin_amdgcn_mfma_f32_16x16x32_bf16(Afh, Bl[nt], acc[mt][nt], 0, 0, 0);
                acc[mt][nt] = __builtin_amdgcn_mfma_f32_16x16x32_bf16(Afl, Bh[nt], acc[mt][nt], 0, 0, 0);
            }
        }
    }

#pragma unroll
    for (int mt = 0; mt < 4; ++mt) {
        int orow = m0 + mt * 16 + q * 4;
#pragma unroll
        for (int nt = 0; nt < NT; ++nt) {
            int col = colbase + nt * 16 + l15;
#pragma unroll
            for (int r = 0; r < 4; ++r) {
                int rr = orow + r;
                if (rr < M) {
                    if (isQ) Q[(size_t)rr * BN + col] = acc[mt][nt][r] + bvs[nt];
                    else P[(size_t)rr * BN + col] = __float2half(acc[mt][nt][r]);
                }
            }
        }
    }
}

// ---------------- fused aggregation 128-dim, fp16 gather (R10 layout, predicated) ----------------
// 2 edges per wave-instruction (32 lanes x 8B = 256B row); 8-edge predicated
// batches keep 4 gathers in flight even on the final partial batch.
__global__ __launch_bounds__(256) void agg_fused128(
    const __half* __restrict__ P, const float* __restrict__ Q,
    const int* __restrict__ row_ptr, const int* __restrict__ csr,
    const float* __restrict__ inv_deg, unsigned short* __restrict__ Hh,
    unsigned short* __restrict__ Hl, int n_nodes) {
    int node = (blockIdx.x * blockDim.x + threadIdx.x) >> 6;
    int lane = threadIdx.x & 63;
    if (node >= n_nodes) return;
    int beg = row_ptr[node], end = row_ptr[node + 1];
    const int half = lane >> 5;
    const int l = lane & 31;
    float a[4][4] = {};
    for (int e = beg; e < end; e += 8) {
#pragma unroll
        for (int j = 0; j < 4; ++j) {
            int idx = e + 2 * j + half;
            int s = csr[min(idx, end - 1)];
            uint2 raw = *(const uint2*)(P + (size_t)s * 128 + l * 4);
            float m = (idx < end) ? 1.f : 0.f;
            float2 f01 = __half22float2(*reinterpret_cast<__half2*>(&raw.x));
            float2 f23 = __half22float2(*reinterpret_cast<__half2*>(&raw.y));
            a[j][0] = fmaf(m, f01.x, a[j][0]);
            a[j][1] = fmaf(m, f01.y, a[j][1]);
            a[j][2] = fmaf(m, f23.x, a[j][2]);
            a[j][3] = fmaf(m, f23.y, a[j][3]);
        }
    }
    float s0 = (a[0][0] + a[1][0]) + (a[2][0] + a[3][0]);
    float s1 = (a[0][1] + a[1][1]) + (a[2][1] + a[3][1]);
    float s2 = (a[0][2] + a[1][2]) + (a[2][2] + a[3][2]);
    float s3 = (a[0][3] + a[1][3]) + (a[2][3] + a[3][3]);
    s0 += __shfl_xor(s0, 32);
    s1 += __shfl_xor(s1, 32);
    s2 += __shfl_xor(s2, 32);
    s3 += __shfl_xor(s3, 32);
    if (lane < 32) {
        float w = inv_deg[node];
        float4 qv = ((const float4*)Q)[(size_t)node * 32 + l];
        float h0 = fmaxf(fmaf(s0, w, qv.x), 0.f);
        float h1 = fmaxf(fmaf(s1, w, qv.y), 0.f);
        float h2 = fmaxf(fmaf(s2, w, qv.z), 0.f);
        float h3 = fmaxf(fmaf(s3, w, qv.w), 0.f);
        ushort4 hv, lv;
        splitf(h0, hv.x, lv.x);
        splitf(h1, hv.y, lv.y);
        splitf(h2, hv.z, lv.z);
        splitf(h3, hv.w, lv.w);
        ((ushort4*)Hh)[(size_t)node * 32 + l] = hv;
        ((ushort4*)Hl)[(size_t)node * 32 + l] = lv;
    }
}

// ---------------- fused aggregation 64-dim + head (R10 layout, predicated, 4-deep) ----------------
// 4 edges per wave-instruction (16 lanes x 8B = 128B row); 16-edge predicated
// batches -> 4 gathers in flight (R11 post-mortem: in-flight count is the lever).
__global__ __launch_bounds__(256) void agg64_head(
    const __half* __restrict__ P, const float* __restrict__ Q,
    const int* __restrict__ row_ptr, const int* __restrict__ csr,
    const float* __restrict__ inv_deg, const float* __restrict__ Wo,
    const float* __restrict__ bo, float* __restrict__ out, int n_nodes) {
    int node = (blockIdx.x * blockDim.x + threadIdx.x) >> 6;
    int lane = threadIdx.x & 63;
    if (node >= n_nodes) return;
    int beg = row_ptr[node], end = row_ptr[node + 1];
    const int quarter = lane >> 4;
    const int l = lane & 15;
    float a[4][4] = {};
    for (int e = beg; e < end; e += 16) {
#pragma unroll
        for (int j = 0; j < 4; ++j) {
            int idx = e + 4 * j + quarter;
            int s = csr[min(idx, end - 1)];
            uint2 raw = *(const uint2*)(P + (size_t)s * 64 + l * 4);
            float m = (idx < end) ? 1.f : 0.f;
            float2 f01 = __half22float2(*reinterpret_cast<__half2*>(&raw.x));
            float2 f23 = __half22float2(*reinterpret_cast<__half2*>(&raw.y));
            a[j][0] = fmaf(m, f01.x, a[j][0]);
            a[j][1] = fmaf(m, f01.y, a[j][1]);
            a[j][2] = fmaf(m, f23.x, a[j][2]);
            a[j][3] = fmaf(m, f23.y, a[j][3]);
        }
    }
    float s0 = (a[0][0] + a[1][0]) + (a[2][0] + a[3][0]);
    float s1 = (a[0][1] + a[1][1]) + (a[2][1] + a[3][1]);
    float s2 = (a[0][2] + a[1][2]) + (a[2][2] + a[3][2]);
    float s3 = (a[0][3] + a[1][3]) + (a[2][3] + a[3][3]);
    s0 += __shfl_xor(s0, 16); s0 += __shfl_xor(s0, 32);
    s1 += __shfl_xor(s1, 16); s1 += __shfl_xor(s1, 32);
    s2 += __shfl_xor(s2, 16); s2 += __shfl_xor(s2, 32);
    s3 += __shfl_xor(s3, 16); s3 += __shfl_xor(s3, 32);
    if (lane < 16) {
        float w = inv_deg[node];
        float4 qv = ((const float4*)Q)[(size_t)node * 16 + l];
        float h0 = fmaxf(fmaf(s0, w, qv.x), 0.f);
        float h1 = fmaxf(fmaf(s1, w, qv.y), 0.f);
        float h2 = fmaxf(fmaf(s2, w, qv.z), 0.f);
        float h3 = fmaxf(fmaf(s3, w, qv.w), 0.f);
        const float4* Wo4 = (const float4*)Wo;
        float4 w0 = Wo4[4 * l + 0], w1 = Wo4[4 * l + 1], w2 = Wo4[4 * l + 2], w3 = Wo4[4 * l + 3];
        float c0 = h0 * w0.x + h1 * w1.x + h2 * w2.x + h3 * w3.x;
        float c1 = h0 * w0.y + h1 * w1.y + h2 * w2.y + h3 * w3.y;
        float c2 = h0 * w0.z + h1 * w1.z + h2 * w2.z + h3 * w3.z;
        float c3 = h0 * w0.w + h1 * w1.w + h2 * w2.w + h3 * w3.w;
#pragma unroll
        for (int m = 8; m > 0; m >>= 1) {
            c0 += __shfl_xor(c0, m);
            c1 += __shfl_xor(c1, m);
            c2 += __shfl_xor(c2, m);
            c3 += __shfl_xor(c3, m);
        }
        if (l == 0) {
            float4 r;
            r.x = c0 + bo[0];
            r.y = c1 + bo[1];
            r.z = c2 + bo[2];
            r.w = c3 + bo[3];
            ((float4*)out)[node] = r;
        }
    }
}

extern "C" void kernel_launch(void* const* d_in, const int* in_sizes, int n_in,
                              void* d_out, int out_size, void* d_ws, size_t ws_size,
                              hipStream_t stream) {
    const float* x = (const float*)d_in[0];
    const int* ei = (const int*)d_in[1];
    const float* wl0 = (const float*)d_in[3];
    const float* wr0 = (const float*)d_in[4];
    const float* b0 = (const float*)d_in[5];
    const float* wl1 = (const float*)d_in[6];
    const float* wr1 = (const float*)d_in[7];
    const float* b1 = (const float*)d_in[8];
    const float* wl2 = (const float*)d_in[9];
    const float* wr2 = (const float*)d_in[10];
    const float* b2 = (const float*)d_in[11];
    const float* wo = (const float*)d_in[12];
    const float* bo = (const float*)d_in[13];

    const int n_nodes = in_sizes[0] / D;   // 50000
    const int n_edges = in_sizes[1] / 2;   // 800000
    const int* srcp = ei;
    const int* dstp = ei + n_edges;

    char* ws = (char*)d_ws;
    size_t off = 0;
    auto carve = [&](size_t bytes) -> void* {
        void* p = ws + off;
        off = (off + bytes + 255) & ~(size_t)255;
        return p;
    };
    int* deg = (int*)carve((size_t)n_nodes * 4);
    int* row_ptr = (int*)carve((size_t)(n_nodes + 1) * 4);
    int* partials = (int*)carve(256 * 4);
    float* inv_deg = (float*)carve((size_t)n_nodes * 4);
    int* csr = (int*)carve((size_t)n_edges * 4);
    __half* Pbuf = (__half*)carve((size_t)n_nodes * D * 2);   // 12.8 MB
    float* Qbuf = (float*)carve((size_t)n_nodes * D * 4);     // 25.6 MB
    unsigned short* hh = (unsigned short*)carve((size_t)n_nodes * D * 2);
    unsigned short* hl = (unsigned short*)carve((size_t)n_nodes * D * 2);
    unsigned short* wt = (unsigned short*)carve((size_t)(4 * 128 * 128 + 2 * 64 * 128) * 2 * 2);
    unsigned short* wl0h = wt;
    unsigned short* wl0l = wl0h + 128 * 128;
    unsigned short* wr0h = wl0l + 128 * 128;
    unsigned short* wr0l = wr0h + 128 * 128;
    unsigned short* wl1h = wr0l + 128 * 128;
    unsigned short* wl1l = wl1h + 128 * 128;
    unsigned short* wr1h = wl1l + 128 * 128;
    unsigned short* wr1l = wr1h + 128 * 128;
    unsigned short* wl2h = wr1l + 128 * 128;
    unsigned short* wl2l = wl2h + 64 * 128;
    unsigned short* wr2h = wl2l + 64 * 128;
    unsigned short* wr2l = wr2h + 64 * 128;

    // CSR-build scratch aliases P/Q (dead until first GEMM):
    const int rr = (n_nodes + NRANGE - 1) / NRANGE;        // 6250
    const int ch = (n_edges + NCHUNK - 1) / NCHUNK;        // 12500
    int* hist = (int*)Qbuf;
    int* basep = (int*)Pbuf;

    const int nchunk_scan = (n_nodes + SCAN_CHUNK - 1) / SCAN_CHUNK;

    hist_count<<<NRANGE * NCHUNK, 1024, 0, stream>>>(dstp, hist, n_edges, n_nodes, rr, ch);
    deg_partial<<<nchunk_scan, 256, 0, stream>>>(hist, deg, partials, n_nodes, rr);
    scan_partials<<<1, 64, 0, stream>>>(partials, nchunk_scan, row_ptr + n_nodes);
    scan_chunks<<<nchunk_scan, 256, 0, stream>>>(deg, partials, row_ptr, inv_deg, n_nodes);
    base_fill<<<(n_nodes + 255) / 256, 256, 0, stream>>>(hist, row_ptr, basep, n_nodes, rr);
    fill_part<<<NRANGE * NCHUNK, 1024, 0, stream>>>(srcp, dstp, basep, csr, n_edges, n_nodes, rr, ch);

    WSplitArgs wa;
    wa.src[0] = wl0; wa.dh[0] = wl0h; wa.dl[0] = wl0l; wa.n[0] = 128;
    wa.src[1] = wr0; wa.dh[1] = wr0h; wa.dl[1] = wr0l; wa.n[1] = 128;
    wa.src[2] = wl1; wa.dh[2] = wl1h; wa.dl[2] = wl1l; wa.n[2] = 128;
    wa.src[3] = wr1; wa.dh[3] = wr1h; wa.dl[3] = wr1l; wa.n[3] = 128;
    wa.src[4] = wl2; wa.dh[4] = wl2h; wa.dl[4] = wl2l; wa.n[4] = 64;
    wa.src[5] = wr2; wa.dh[5] = wr2h; wa.dl[5] = wr2l; wa.n[5] = 64;
    split_w<<<dim3(64, 6), 256, 0, stream>>>(wa);

    const int agg_blocks = (n_nodes * 64 + 255) / 256;
    const int gemm_blocks = (n_nodes + 63) / 64;   // 782

    // layer 0: A = x (fp32, split during LDS staging)
    gemm_lds<128, 4, true><<<gemm_blocks, 256, 0, stream>>>(
        x, nullptr, nullptr, wl0h, wl0l, wr0h, wr0l, b0, Pbuf, Qbuf, n_nodes);
    agg_fused128<<<agg_blocks, 256, 0, stream>>>(Pbuf, Qbuf, row_ptr, csr, inv_deg, hh, hl, n_nodes);
    // layer 1
    gemm_lds<128, 4, false><<<gemm_blocks, 256, 0, stream>>>(
        nullptr, hh, hl, wl1h, wl1l, wr1h, wr1l, b1, Pbuf, Qbuf, n_nodes);
    agg_fused128<<<agg_blocks, 256, 0, stream>>>(Pbuf, Qbuf, row_ptr, csr, inv_deg, hh, hl, n_nodes);
    // layer 2 (each matrix 64 cols)
    gemm_lds<64, 2, false><<<gemm_blocks, 256, 0, stream>>>(
        nullptr, hh, hl, wl2h, wl2l, wr2h, wr2l, b2, Pbuf, Qbuf, n_nodes);
    agg64_head<<<agg_blocks, 256, 0, stream>>>(Pbuf, Qbuf, row_ptr, csr, inv_deg,
                                               wo, bo, (float*)d_out, n_nodes);
}